// Round 9
// baseline (159.696 us; speedup 1.0000x reference)
//
#include <hip/hip_runtime.h>
#include <hip/hip_bf16.h>
#include <stdint.h>

// Problem constants: B=8, T=2048, C=1024 (n_embd), H=128 (head dim)
#define BB 8
#define TT 2048
#define CC 1024
#define HH 128

typedef __attribute__((ext_vector_type(8))) short bf16x8;
typedef __attribute__((ext_vector_type(8))) unsigned short u16x8;
typedef __attribute__((ext_vector_type(4))) float f32x4;

static __device__ __forceinline__ unsigned short f2bf(float f) {
    union { float f; uint32_t u; } v; v.f = f;
    return (unsigned short)((v.u + 0x7fffu + ((v.u >> 16) & 1u)) >> 16);  // RNE
}

#define GLOBAL_AS __attribute__((address_space(1)))
#define LDS_AS    __attribute__((address_space(3)))
static __device__ __forceinline__ void async16(const void* g, void* l) {
    // global->LDS DMA, 16 B/lane; LDS dest = wave-uniform base + lane*16
    __builtin_amdgcn_global_load_lds((const GLOBAL_AS void*)g, (LDS_AS void*)l, 16, 0, 0);
}

// ---------------------------------------------------------------------------
// Fragment-tiled layouts (u16 units):
//  QF/KF: 16x32 (rows x dims) subtiles, 1 KB each, internal [qd(dim4)][ln(row16)][j(dim8)]
//    addr = ((grow>>4)*4 + dim>>5)*512 + ((dim>>3)&3)*128 + (grow&15)*8 + (dim&7)
//    where grow = b*2048 + t  (global row). A wave lane l=qd*16+ln reads its
//    MFMA A/B fragment at blockbase + l*8 -- perfectly coalesced.
//  VF: 32x16 (keys x h) subtiles, internal [qd(key4)][ln(h16)][j(key8)]
//    addr = ((b*64 + key>>5)*8 + h>>4)*512 + ((key>>3)&3)*128 + (h&15)*8 + (key&7)
// ---------------------------------------------------------------------------

// ---------------------------------------------------------------------------
// Kernel 0: W fp32 [k][n] -> bf16 Wb [3*128 n][1024 k]  (k-contiguous rows)
// ---------------------------------------------------------------------------
__global__ __launch_bounds__(256) void wconv(
    const float* __restrict__ Wq, const float* __restrict__ Wk,
    const float* __restrict__ Wv, unsigned short* __restrict__ Wb)
{
    int u = blockIdx.x * 256 + threadIdx.x;
    if (u >= 3 * 128 * 128) return;
    int kc = u & 127, n = (u >> 7) & 127, mat = u >> 14;
    const float* W = (mat == 0) ? Wq : (mat == 1) ? Wk : Wv;
    const float* s = W + (size_t)(kc * 8) * HH + n;
    u16x8 v;
    #pragma unroll
    for (int j = 0; j < 8; j++) v[j] = f2bf(s[(size_t)j * HH]);
    *(u16x8*)(Wb + ((size_t)mat * HH + n) * CC + kc * 8) = v;
}

// ---------------------------------------------------------------------------
// Kernel 1: fused QKV projection. BM=64, 512 threads (8 waves = 2 m-halves x
// 4 n-quarters, each 32m x 96n, 24 MFMA/step), grid 256. BK=64, XOR-swizzled
// Bs via async16; x reg-prefetch after barrier. R15: epilogue now emits
// Q/K/V in FRAGMENT-TILED global layout (QF/KF/VF) so attn loads fragments
// with coalesced dwordx4 -- same store count, remapped addresses only.
// ---------------------------------------------------------------------------
#define BS_U16 4608              // As = 64 rows * 72 pitch
#define EQ_OFF 0
#define EK_OFF 8704
#define EV_OFF 17408
__global__ __launch_bounds__(512) void qkv_proj(
    const float* __restrict__ x, const unsigned short* __restrict__ Wb,
    unsigned short* __restrict__ QF, unsigned short* __restrict__ KF,
    unsigned short* __restrict__ VF)
{
    __shared__ __align__(16) unsigned short lds[29184];   // 58.37 KB

    const int m0  = blockIdx.x * 64;
    const int tid = threadIdx.x;
    const int lane = tid & 63;
    const int w    = tid >> 6;       // 0..7
    const int qd   = lane >> 4;
    const int ln   = lane & 15;
    const int wm   = w & 1;          // m half (32 rows)
    const int wn   = w >> 1;         // n quarter (96 cols)

    f32x4 acc[2][6];
    #pragma unroll
    for (int i = 0; i < 2; i++)
        #pragma unroll
        for (int j = 0; j < 6; j++) acc[i][j] = (f32x4){0.f,0.f,0.f,0.f};

    const int xr = tid >> 3;         // 0..63 row
    const int xg = (tid & 7) * 8;    // col offset (8 floats / thread)

    float4 xf[2];
    {
        const float* s = x + (size_t)(m0 + xr) * CC + xg;
        xf[0] = ((const float4*)s)[0];
        xf[1] = ((const float4*)s)[1];
    }

    for (int k0 = 0; k0 < CC; k0 += 64) {
        {
            u16x8 v0;
            v0[0]=f2bf(xf[0].x); v0[1]=f2bf(xf[0].y); v0[2]=f2bf(xf[0].z); v0[3]=f2bf(xf[0].w);
            v0[4]=f2bf(xf[1].x); v0[5]=f2bf(xf[1].y); v0[6]=f2bf(xf[1].z); v0[7]=f2bf(xf[1].w);
            *(u16x8*)&lds[xr * 72 + xg] = v0;
        }
        // Bs: 384 rows x 64 k (bf16), 16B chunks, XOR swizzle (^row&7).
        #pragma unroll
        for (int i = 0; i < 6; i++) {
            int sb = i * 512 + w * 64;
            int slot = sb + lane;
            int row = slot >> 3, j = (slot & 7) ^ (row & 7);
            async16(Wb + (size_t)row * CC + k0 + j * 8, &lds[BS_U16 + sb * 8]);
        }
        __syncthreads();
        if (k0 + 64 < CC) {
            const float* s = x + (size_t)(m0 + xr) * CC + k0 + 64 + xg;
            xf[0] = ((const float4*)s)[0];
            xf[1] = ((const float4*)s)[1];
        }
        #pragma unroll
        for (int ks = 0; ks < 2; ks++) {
            bf16x8 a0 = *(const bf16x8*)&lds[(wm*32 + ln) * 72 + ks*32 + qd*8];
            bf16x8 a1 = *(const bf16x8*)&lds[(wm*32 + 16 + ln) * 72 + ks*32 + qd*8];
            #pragma unroll
            for (int nf = 0; nf < 6; nf++) {
                int row = wn * 96 + nf * 16 + ln;
                int ch  = (ks * 4 + qd) ^ (row & 7);
                bf16x8 b = *(const bf16x8*)&lds[BS_U16 + (row * 8 + ch) * 8];
                acc[0][nf] = __builtin_amdgcn_mfma_f32_16x16x32_bf16(a0, b, acc[0][nf], 0, 0, 0);
                acc[1][nf] = __builtin_amdgcn_mfma_f32_16x16x32_bf16(a1, b, acc[1][nf], 0, 0, 0);
            }
        }
        __syncthreads();
    }

    // epilogue: scatter acc -> LDS (Q/K row-major pitch 136; V transposed pitch 72)
    #pragma unroll
    for (int mf = 0; mf < 2; mf++)
        #pragma unroll
        for (int nf = 0; nf < 6; nf++) {
            int n = wn * 96 + nf * 16;
            int mat = n >> 7, hb = n & 127;
            #pragma unroll
            for (int r = 0; r < 4; r++) {
                unsigned short v = f2bf(acc[mf][nf][r]);
                int mrow = wm*32 + mf*16 + qd*4 + r;       // 0..63
                if (mat < 2) lds[(mat ? EK_OFF : EQ_OFF) + mrow * 136 + hb + ln] = v;
                else         lds[EV_OFF + (hb + ln) * 72 + mrow] = v;
            }
        }
    __syncthreads();
    // Q/K -> fragment-tiled QF/KF
    {
        int rr = tid >> 3, c0 = (tid & 7) * 16;            // 64 rows x 8 thr
        int kbg = (m0 + rr) >> 4, lnr = rr & 15;           // global 16-row block
        #pragma unroll
        for (int i = 0; i < 2; i++) {
            int c8 = (c0 >> 3) + i;                        // dim/8 chunk index
            int db = c8 >> 2, qdw = c8 & 3;
            size_t a = ((size_t)kbg * 4 + db) * 512 + qdw * 128 + lnr * 8;
            u16x8 vq = *(const u16x8*)&lds[EQ_OFF + rr * 136 + c0 + i * 8];
            *(u16x8*)(QF + a) = vq;
            u16x8 vk = *(const u16x8*)&lds[EK_OFF + rr * 136 + c0 + i * 8];
            *(u16x8*)(KF + a) = vk;
        }
    }
    // V -> fragment-tiled VF (keys x h subtiles)
    {
        int bb = m0 >> 11, t0 = m0 & (TT - 1);
        int hh = tid >> 2, tf = (tid & 3) * 16;            // 128 h x 4 thr
        #pragma unroll
        for (int i = 0; i < 2; i++) {
            int k0 = t0 + tf + i * 8;
            size_t a = (((size_t)(bb * 64 + (k0 >> 5))) * 8 + (hh >> 4)) * 512
                     + ((k0 >> 3) & 3) * 128 + (hh & 15) * 8;
            u16x8 vv = *(const u16x8*)&lds[EV_OFF + hh * 72 + tf + i * 8];
            *(u16x8*)(VF + a) = vv;
        }
    }
}

// ---------------------------------------------------------------------------
// Kernel 2: flash attention (causal), no-max softmax, FRAGMENT-DIRECT.
// R15: attn rate was invariant (~10.4K cy per 64q x 128k slab) across
// occupancy/barrier/DS-op/balance variants -> the sync stage+drain skeleton
// itself is the cost. Now K/V/Q fragments load straight from L2-resident
// fragment-tiled buffers (coalesced dwordx4, lane l at base+l*16): NO LDS
// staging, NO DMA, NO main-loop barriers (R11's idea minus its 16-line
// gathers). P round-trip stays in same-wave private LDS. Block = 32 q-rows,
// 256 thr, 4 waves = key quarters; QBLK=32, grid 512, complementary qt
// pairing (co-resident pair sums to 17 steps on every CU; no barriers ->
// waves interleave freely). LDS 43.5 KB static. In-block 4-way merge.
// ---------------------------------------------------------------------------
__global__ __launch_bounds__(256) void attn(
    const unsigned short* __restrict__ QF, const unsigned short* __restrict__ KF,
    const unsigned short* __restrict__ VF, float* __restrict__ out)
{
    __shared__ __align__(16) _Float16 Om[4][32 * 128];       // 32 KB merge buffer
    __shared__ __align__(16) unsigned short Ps[4][32 * 40];  // 10 KB, per-wave P
    __shared__ float Lp[4][32];

    const int tid  = threadIdx.x;
    const int lane = tid & 63;
    const int wave = tid >> 6;            // 0..3 = key quarter
    const int qd = lane >> 4;
    const int ln = lane & 15;
    const int kq = wave;

    const int bx = blockIdx.x;
    int b, qt;
    if (bx < 256) { b = bx & 7;               qt = 63 - (bx >> 3); }  // long, desc
    else          { int u = bx - 256; b = u & 7; qt = u >> 3; }       // short, asc
    const int qbase = qt * 32;
    const int nst = (qt + 4) >> 2;        // 128-key steps; nst*128 <= 2048

    // Q fragments: QF block (b*128 + qt*2 + qs)*4 + c, lane offset l*8
    bf16x8 aq[2][4];
    {
        const unsigned short* qp = QF + ((size_t)(b * 128 + qt * 2) * 4) * 512 + lane * 8;
        #pragma unroll
        for (int qs = 0; qs < 2; qs++)
            #pragma unroll
            for (int c = 0; c < 4; c++)
                aq[qs][c] = *(const bf16x8*)(qp + (qs * 4 + c) * 512);
    }

    f32x4 O[2][8];
    float lsum[2][4];
    #pragma unroll
    for (int qs = 0; qs < 2; qs++) {
        #pragma unroll
        for (int h = 0; h < 8; h++) O[qs][h] = (f32x4){0.f,0.f,0.f,0.f};
        #pragma unroll
        for (int r = 0; r < 4; r++) lsum[qs][r] = 0.f;
    }

    const float sl   = 0.08838834764831843f * 1.4426950408889634f; // (1/sqrt128)*log2e
    const float M0L2 = 7.2134752044448f;                           // 5.0*log2(e)
    unsigned short* ps = Ps[wave];

    // per-step strides: KF step = 8 blocks * 2048 u16 = 16384; VF same.
    const unsigned short* kp = KF + (size_t)(b * 128 + kq * 2) * 2048 + lane * 8;
    const unsigned short* vp = VF + (size_t)(b * 64 + kq) * 4096 + lane * 8;

    for (int st = 0; st < nst; st++) {
        const int s0 = st * 128;
        const unsigned short* kst = kp + (size_t)st * 16384;
        const unsigned short* vst = vp + (size_t)st * 16384;

        // ---- S = Q K^T : 32 q x 32 keys; coalesced fragment loads ----
        f32x4 s[2][2];
        s[0][0] = (f32x4){0.f,0.f,0.f,0.f}; s[0][1] = (f32x4){0.f,0.f,0.f,0.f};
        s[1][0] = (f32x4){0.f,0.f,0.f,0.f}; s[1][1] = (f32x4){0.f,0.f,0.f,0.f};
        #pragma unroll
        for (int nt = 0; nt < 2; nt++) {
            #pragma unroll
            for (int c = 0; c < 4; c++) {
                bf16x8 bk = *(const bf16x8*)(kst + nt * 2048 + c * 512);
                s[0][nt] = __builtin_amdgcn_mfma_f32_16x16x32_bf16(aq[0][c], bk, s[0][nt], 0, 0, 0);
                s[1][nt] = __builtin_amdgcn_mfma_f32_16x16x32_bf16(aq[1][c], bk, s[1][nt], 0, 0, 0);
            }
        }
        // ---- exp2 + causal mask; per-lane l; P -> private LDS (pitch 40) ----
        #pragma unroll
        for (int qs = 0; qs < 2; qs++)
            #pragma unroll
            for (int nt = 0; nt < 2; nt++) {
                int col = s0 + kq * 32 + nt * 16 + ln;
                #pragma unroll
                for (int r = 0; r < 4; r++) {
                    int row = qbase + qs * 16 + qd * 4 + r;
                    float e = __builtin_amdgcn_exp2f(s[qs][nt][r] * sl - M0L2);
                    e = (col <= row) ? e : 0.f;
                    lsum[qs][r] += e;
                    ps[(qs*16 + qd*4 + r) * 40 + nt*16 + ln] = f2bf(e);
                }
            }
        // ---- P in A-layout (own slice; same-wave DS is in-order) ----
        bf16x8 ap0 = *(const bf16x8*)&ps[ln * 40 + qd * 8];
        bf16x8 ap1 = *(const bf16x8*)&ps[(16 + ln) * 40 + qd * 8];
        // ---- O += P V; coalesced V fragment loads ----
        #pragma unroll
        for (int ht = 0; ht < 8; ht++) {
            bf16x8 bv = *(const bf16x8*)(vst + ht * 512);
            O[0][ht] = __builtin_amdgcn_mfma_f32_16x16x32_bf16(ap0, bv, O[0][ht], 0, 0, 0);
            O[1][ht] = __builtin_amdgcn_mfma_f32_16x16x32_bf16(ap1, bv, O[1][ht], 0, 0, 0);
        }
    }

    // ---- end: l reduce over ln lanes; O (fp16) into merge buffer ----
    #pragma unroll
    for (int qs = 0; qs < 2; qs++)
        #pragma unroll
        for (int r = 0; r < 4; r++) {
            float sum = lsum[qs][r];
            #pragma unroll
            for (int off = 1; off < 16; off <<= 1)
                sum += __shfl_xor(sum, off, 64);
            if (ln == 0) Lp[wave][qs*16 + qd*4 + r] = sum;
        }
    _Float16* om = &Om[wave][0];
    #pragma unroll
    for (int qs = 0; qs < 2; qs++)
        #pragma unroll
        for (int ht = 0; ht < 8; ht++)
            #pragma unroll
            for (int r = 0; r < 4; r++)
                om[(qs*16 + qd*4 + r) * 128 + ht*16 + ln] = (_Float16)O[qs][ht][r];
    __syncthreads();

    // ---- 4-way merge (key quarters) + write: 32 rows x 8 thr, 16 h each ----
    {
        int row = tid >> 3, h0 = (tid & 7) * 16;
        float L = Lp[0][row] + Lp[1][row] + Lp[2][row] + Lp[3][row];
        float inv = 1.0f / L;
        const _Float16* p0 = &Om[0][row * 128 + h0];
        const _Float16* p1 = &Om[1][row * 128 + h0];
        const _Float16* p2 = &Om[2][row * 128 + h0];
        const _Float16* p3 = &Om[3][row * 128 + h0];
        float* op = out + ((size_t)b * TT + qt * 32 + row) * HH + h0;
        #pragma unroll
        for (int i = 0; i < 4; i++) {
            float4 v;
            v.x = (((float)p0[i*4+0] + (float)p1[i*4+0]) + ((float)p2[i*4+0] + (float)p3[i*4+0])) * inv;
            v.y = (((float)p0[i*4+1] + (float)p1[i*4+1]) + ((float)p2[i*4+1] + (float)p3[i*4+1])) * inv;
            v.z = (((float)p0[i*4+2] + (float)p1[i*4+2]) + ((float)p2[i*4+2] + (float)p3[i*4+2])) * inv;
            v.w = (((float)p0[i*4+3] + (float)p1[i*4+3]) + ((float)p2[i*4+3] + (float)p3[i*4+3])) * inv;
            ((float4*)op)[i] = v;
        }
    }
}

// ---------------------------------------------------------------------------
extern "C" void kernel_launch(void* const* d_in, const int* in_sizes, int n_in,
                              void* d_out, int out_size, void* d_ws, size_t ws_size,
                              hipStream_t stream) {
    const float* x  = (const float*)d_in[0];
    const float* Wq = (const float*)d_in[1];
    const float* Wk = (const float*)d_in[2];
    const float* Wv = (const float*)d_in[3];

    // workspace (u16): Wb [384][1024]; QF, KF, VF fragment-tiled (2M u16 each)
    unsigned short* Wb = (unsigned short*)d_ws;
    unsigned short* QFw = Wb + (size_t)3 * HH * CC;
    unsigned short* KFw = QFw + (size_t)BB * TT * HH;
    unsigned short* VFw = KFw + (size_t)BB * TT * HH;

    wconv<<<dim3(192), 256, 0, stream>>>(Wq, Wk, Wv, Wb);
    qkv_proj<<<dim3(256), 512, 0, stream>>>(x, Wb, QFw, KFw, VFw);
    attn<<<dim3(512), 256, 0, stream>>>(QFw, KFw, VFw, (float*)d_out);
}

// Round 10
// 156.000 us; speedup vs baseline: 1.0237x; 1.0237x over previous
//
#include <hip/hip_runtime.h>
#include <hip/hip_bf16.h>
#include <stdint.h>

// Problem constants: B=8, T=2048, C=1024 (n_embd), H=128 (head dim)
#define BB 8
#define TT 2048
#define CC 1024
#define HH 128

typedef __attribute__((ext_vector_type(8))) short bf16x8;
typedef __attribute__((ext_vector_type(8))) unsigned short u16x8;
typedef __attribute__((ext_vector_type(4))) float f32x4;

static __device__ __forceinline__ unsigned short f2bf(float f) {
    union { float f; uint32_t u; } v; v.f = f;
    return (unsigned short)((v.u + 0x7fffu + ((v.u >> 16) & 1u)) >> 16);  // RNE
}

#define GLOBAL_AS __attribute__((address_space(1)))
#define LDS_AS    __attribute__((address_space(3)))
static __device__ __forceinline__ void async16(const void* g, void* l) {
    // global->LDS DMA, 16 B/lane; LDS dest = wave-uniform base + lane*16
    __builtin_amdgcn_global_load_lds((const GLOBAL_AS void*)g, (LDS_AS void*)l, 16, 0, 0);
}

// ---------------------------------------------------------------------------
// Fragment-tiled layouts (u16 units):
//  QF/KF: 16x32 (rows x dims) subtiles, 1 KB each, internal [qd(dim4)][ln(row16)][j(dim8)]
//    addr = ((grow>>4)*4 + dim>>5)*512 + ((dim>>3)&3)*128 + (grow&15)*8 + (dim&7)
//  VF: 32x16 (keys x h) subtiles, internal [qd(key4)][ln(h16)][j(key8)]
//    addr = ((b*64 + key>>5)*8 + h>>4)*512 + ((key>>3)&3)*128 + (h&15)*8 + (key&7)
// ---------------------------------------------------------------------------

// ---------------------------------------------------------------------------
// Kernel 0: W fp32 [k][n] -> bf16 Wb [3*128 n][1024 k]  (k-contiguous rows)
// ---------------------------------------------------------------------------
__global__ __launch_bounds__(256) void wconv(
    const float* __restrict__ Wq, const float* __restrict__ Wk,
    const float* __restrict__ Wv, unsigned short* __restrict__ Wb)
{
    int u = blockIdx.x * 256 + threadIdx.x;
    if (u >= 3 * 128 * 128) return;
    int kc = u & 127, n = (u >> 7) & 127, mat = u >> 14;
    const float* W = (mat == 0) ? Wq : (mat == 1) ? Wk : Wv;
    const float* s = W + (size_t)(kc * 8) * HH + n;
    u16x8 v;
    #pragma unroll
    for (int j = 0; j < 8; j++) v[j] = f2bf(s[(size_t)j * HH]);
    *(u16x8*)(Wb + ((size_t)mat * HH + n) * CC + kc * 8) = v;
}

// ---------------------------------------------------------------------------
// Kernel 1: fused QKV projection. BM=64, 512 threads (8 waves = 2 m-halves x
// 4 n-quarters, each 32m x 96n, 24 MFMA/step), grid 256. BK=64, XOR-swizzled
// Bs via async16; x reg-prefetch after barrier. Emits fragment-tiled QF/KF/VF.
// Unchanged this round.
// ---------------------------------------------------------------------------
#define BS_U16 4608              // As = 64 rows * 72 pitch
#define EQ_OFF 0
#define EK_OFF 8704
#define EV_OFF 17408
__global__ __launch_bounds__(512) void qkv_proj(
    const float* __restrict__ x, const unsigned short* __restrict__ Wb,
    unsigned short* __restrict__ QF, unsigned short* __restrict__ KF,
    unsigned short* __restrict__ VF)
{
    __shared__ __align__(16) unsigned short lds[29184];   // 58.37 KB

    const int m0  = blockIdx.x * 64;
    const int tid = threadIdx.x;
    const int lane = tid & 63;
    const int w    = tid >> 6;       // 0..7
    const int qd   = lane >> 4;
    const int ln   = lane & 15;
    const int wm   = w & 1;          // m half (32 rows)
    const int wn   = w >> 1;         // n quarter (96 cols)

    f32x4 acc[2][6];
    #pragma unroll
    for (int i = 0; i < 2; i++)
        #pragma unroll
        for (int j = 0; j < 6; j++) acc[i][j] = (f32x4){0.f,0.f,0.f,0.f};

    const int xr = tid >> 3;         // 0..63 row
    const int xg = (tid & 7) * 8;    // col offset (8 floats / thread)

    float4 xf[2];
    {
        const float* s = x + (size_t)(m0 + xr) * CC + xg;
        xf[0] = ((const float4*)s)[0];
        xf[1] = ((const float4*)s)[1];
    }

    for (int k0 = 0; k0 < CC; k0 += 64) {
        {
            u16x8 v0;
            v0[0]=f2bf(xf[0].x); v0[1]=f2bf(xf[0].y); v0[2]=f2bf(xf[0].z); v0[3]=f2bf(xf[0].w);
            v0[4]=f2bf(xf[1].x); v0[5]=f2bf(xf[1].y); v0[6]=f2bf(xf[1].z); v0[7]=f2bf(xf[1].w);
            *(u16x8*)&lds[xr * 72 + xg] = v0;
        }
        // Bs: 384 rows x 64 k (bf16), 16B chunks, XOR swizzle (^row&7).
        #pragma unroll
        for (int i = 0; i < 6; i++) {
            int sb = i * 512 + w * 64;
            int slot = sb + lane;
            int row = slot >> 3, j = (slot & 7) ^ (row & 7);
            async16(Wb + (size_t)row * CC + k0 + j * 8, &lds[BS_U16 + sb * 8]);
        }
        __syncthreads();
        if (k0 + 64 < CC) {
            const float* s = x + (size_t)(m0 + xr) * CC + k0 + 64 + xg;
            xf[0] = ((const float4*)s)[0];
            xf[1] = ((const float4*)s)[1];
        }
        #pragma unroll
        for (int ks = 0; ks < 2; ks++) {
            bf16x8 a0 = *(const bf16x8*)&lds[(wm*32 + ln) * 72 + ks*32 + qd*8];
            bf16x8 a1 = *(const bf16x8*)&lds[(wm*32 + 16 + ln) * 72 + ks*32 + qd*8];
            #pragma unroll
            for (int nf = 0; nf < 6; nf++) {
                int row = wn * 96 + nf * 16 + ln;
                int ch  = (ks * 4 + qd) ^ (row & 7);
                bf16x8 b = *(const bf16x8*)&lds[BS_U16 + (row * 8 + ch) * 8];
                acc[0][nf] = __builtin_amdgcn_mfma_f32_16x16x32_bf16(a0, b, acc[0][nf], 0, 0, 0);
                acc[1][nf] = __builtin_amdgcn_mfma_f32_16x16x32_bf16(a1, b, acc[1][nf], 0, 0, 0);
            }
        }
        __syncthreads();
    }

    // epilogue: scatter acc -> LDS (Q/K row-major pitch 136; V transposed pitch 72)
    #pragma unroll
    for (int mf = 0; mf < 2; mf++)
        #pragma unroll
        for (int nf = 0; nf < 6; nf++) {
            int n = wn * 96 + nf * 16;
            int mat = n >> 7, hb = n & 127;
            #pragma unroll
            for (int r = 0; r < 4; r++) {
                unsigned short v = f2bf(acc[mf][nf][r]);
                int mrow = wm*32 + mf*16 + qd*4 + r;       // 0..63
                if (mat < 2) lds[(mat ? EK_OFF : EQ_OFF) + mrow * 136 + hb + ln] = v;
                else         lds[EV_OFF + (hb + ln) * 72 + mrow] = v;
            }
        }
    __syncthreads();
    // Q/K -> fragment-tiled QF/KF
    {
        int rr = tid >> 3, c0 = (tid & 7) * 16;            // 64 rows x 8 thr
        int kbg = (m0 + rr) >> 4, lnr = rr & 15;           // global 16-row block
        #pragma unroll
        for (int i = 0; i < 2; i++) {
            int c8 = (c0 >> 3) + i;                        // dim/8 chunk index
            int db = c8 >> 2, qdw = c8 & 3;
            size_t a = ((size_t)kbg * 4 + db) * 512 + qdw * 128 + lnr * 8;
            u16x8 vq = *(const u16x8*)&lds[EQ_OFF + rr * 136 + c0 + i * 8];
            *(u16x8*)(QF + a) = vq;
            u16x8 vk = *(const u16x8*)&lds[EK_OFF + rr * 136 + c0 + i * 8];
            *(u16x8*)(KF + a) = vk;
        }
    }
    // V -> fragment-tiled VF (keys x h subtiles)
    {
        int bb = m0 >> 11, t0 = m0 & (TT - 1);
        int hh = tid >> 2, tf = (tid & 3) * 16;            // 128 h x 4 thr
        #pragma unroll
        for (int i = 0; i < 2; i++) {
            int k0 = t0 + tf + i * 8;
            size_t a = (((size_t)(bb * 64 + (k0 >> 5))) * 8 + (hh >> 4)) * 512
                     + ((k0 >> 3) & 3) * 128 + (hh & 15) * 8;
            u16x8 vv = *(const u16x8*)&lds[EV_OFF + hh * 72 + tf + i * 8];
            *(u16x8*)(VF + a) = vv;
        }
    }
}

// ---------------------------------------------------------------------------
// Kernel 2: flash attention (causal), no-max softmax, FRAGMENT-DIRECT.
// R16 discriminating experiment. Cross-round law: wall = wave-steps/SIMD x
// ~2900 cy per 16qx128k of wave-work, in BOTH lockstep-staged (R9/R12,
// 4 w/SIMD) and barrier-free (R15, 2 w/SIMD) forms. Hypothesis 1: barriers
// lockstep waves so latency chains stack; R15 failed only for lack of waves.
// Test: barrier-free + 8x16q waves/block -> 4096 waves = 4 waves/SIMD.
// If chains overlap -> ~25 us. If neutral -> per-wave rate is intrinsic;
// pivot to instruction-count reduction (32x32 swapped QK + in-reg softmax).
// Block = 32 q-rows, 512 thr, 8 waves = (qgrp x2) x (kq x4). QBLK=32,
// grid 512, complementary qt pairing. LDS 43.5 KB. In-block 8-way merge.
// ---------------------------------------------------------------------------
__global__ __launch_bounds__(512) void attn(
    const unsigned short* __restrict__ QF, const unsigned short* __restrict__ KF,
    const unsigned short* __restrict__ VF, float* __restrict__ out)
{
    __shared__ __align__(16) _Float16 Om[8][16 * 128];       // 32 KB merge buffer
    __shared__ __align__(16) unsigned short Ps[8][16 * 40];  // 10 KB, per-wave P
    __shared__ float Lp[8][16];

    const int tid  = threadIdx.x;
    const int lane = tid & 63;
    const int wave = tid >> 6;            // 0..7
    const int qd = lane >> 4;
    const int ln = lane & 15;
    const int qgrp = wave >> 2;           // 0..1: q rows qgrp*16..+16
    const int kq   = wave & 3;            // key quarter (32 keys of 128)

    const int bx = blockIdx.x;
    int b, qt;
    if (bx < 256) { b = bx & 7;               qt = 63 - (bx >> 3); }  // long, desc
    else          { int u = bx - 256; b = u & 7; qt = u >> 3; }       // short, asc
    const int qrow0 = qt * 32 + qgrp * 16;
    const int nst = (qt + 4) >> 2;        // 128-key steps; nst*128 <= 2048

    // Q fragments: QF block (b*128 + qt*2 + qgrp)*4 + c, lane offset l*8
    bf16x8 aq[4];
    {
        const unsigned short* qp = QF + ((size_t)(b * 128 + qt * 2 + qgrp) * 4) * 512 + lane * 8;
        #pragma unroll
        for (int c = 0; c < 4; c++)
            aq[c] = *(const bf16x8*)(qp + c * 512);
    }

    f32x4 O[8];
    float lsum[4];
    #pragma unroll
    for (int h = 0; h < 8; h++) O[h] = (f32x4){0.f,0.f,0.f,0.f};
    #pragma unroll
    for (int r = 0; r < 4; r++) lsum[r] = 0.f;

    const float sl   = 0.08838834764831843f * 1.4426950408889634f; // (1/sqrt128)*log2e
    const float M0L2 = 7.2134752044448f;                           // 5.0*log2(e)
    unsigned short* ps = Ps[wave];

    // per-step strides: KF/VF step = 8 blocks * 2048 u16 = 16384.
    const unsigned short* kp = KF + (size_t)(b * 128 + kq * 2) * 2048 + lane * 8;
    const unsigned short* vp = VF + (size_t)(b * 64 + kq) * 4096 + lane * 8;

    for (int st = 0; st < nst; st++) {
        const int s0 = st * 128;
        const unsigned short* kst = kp + (size_t)st * 16384;
        const unsigned short* vst = vp + (size_t)st * 16384;

        // ---- S = Q K^T : 16 q x 32 keys; coalesced fragment loads ----
        f32x4 s[2] = {(f32x4){0.f,0.f,0.f,0.f}, (f32x4){0.f,0.f,0.f,0.f}};
        #pragma unroll
        for (int nt = 0; nt < 2; nt++) {
            #pragma unroll
            for (int c = 0; c < 4; c++) {
                bf16x8 bk = *(const bf16x8*)(kst + nt * 2048 + c * 512);
                s[nt] = __builtin_amdgcn_mfma_f32_16x16x32_bf16(aq[c], bk, s[nt], 0, 0, 0);
            }
        }
        // ---- exp2 + causal mask; per-lane l; P -> private LDS (pitch 40) ----
        #pragma unroll
        for (int nt = 0; nt < 2; nt++) {
            int col = s0 + kq * 32 + nt * 16 + ln;
            #pragma unroll
            for (int r = 0; r < 4; r++) {
                int row = qrow0 + qd * 4 + r;
                float e = __builtin_amdgcn_exp2f(s[nt][r] * sl - M0L2);
                e = (col <= row) ? e : 0.f;
                lsum[r] += e;
                ps[(qd*4 + r) * 40 + nt*16 + ln] = f2bf(e);
            }
        }
        // ---- P in A-layout (own slice; same-wave DS is in-order) ----
        bf16x8 ap = *(const bf16x8*)&ps[ln * 40 + qd * 8];
        // ---- O += P V; coalesced V fragment loads ----
        #pragma unroll
        for (int ht = 0; ht < 8; ht++) {
            bf16x8 bv = *(const bf16x8*)(vst + ht * 512);
            O[ht] = __builtin_amdgcn_mfma_f32_16x16x32_bf16(ap, bv, O[ht], 0, 0, 0);
        }
    }

    // ---- end: l reduce over ln lanes; O (fp16) into merge buffer ----
    #pragma unroll
    for (int r = 0; r < 4; r++) {
        float sum = lsum[r];
        #pragma unroll
        for (int off = 1; off < 16; off <<= 1)
            sum += __shfl_xor(sum, off, 64);
        if (ln == 0) Lp[wave][qd*4 + r] = sum;
    }
    _Float16* om = &Om[wave][0];
    #pragma unroll
    for (int ht = 0; ht < 8; ht++)
        #pragma unroll
        for (int r = 0; r < 4; r++)
            om[(qd*4 + r) * 128 + ht*16 + ln] = (_Float16)O[ht][r];
    __syncthreads();

    // ---- 4-way merge (key quarters) + write: 32 rows x 16 thr, 8 h each ----
    {
        int row = tid >> 4, h0 = (tid & 15) * 8;
        int g = row >> 4, rl = row & 15;       // g = qgrp of this row
        float L = Lp[g*4 + 0][rl] + Lp[g*4 + 1][rl]
                + Lp[g*4 + 2][rl] + Lp[g*4 + 3][rl];
        float inv = 1.0f / L;
        const _Float16* p0 = &Om[g*4 + 0][rl * 128 + h0];
        const _Float16* p1 = &Om[g*4 + 1][rl * 128 + h0];
        const _Float16* p2 = &Om[g*4 + 2][rl * 128 + h0];
        const _Float16* p3 = &Om[g*4 + 3][rl * 128 + h0];
        float* op = out + ((size_t)b * TT + qt * 32 + row) * HH + h0;
        #pragma unroll
        for (int i = 0; i < 2; i++) {
            float4 v;
            v.x = (((float)p0[i*4+0] + (float)p1[i*4+0]) + ((float)p2[i*4+0] + (float)p3[i*4+0])) * inv;
            v.y = (((float)p0[i*4+1] + (float)p1[i*4+1]) + ((float)p2[i*4+1] + (float)p3[i*4+1])) * inv;
            v.z = (((float)p0[i*4+2] + (float)p1[i*4+2]) + ((float)p2[i*4+2] + (float)p3[i*4+2])) * inv;
            v.w = (((float)p0[i*4+3] + (float)p1[i*4+3]) + ((float)p2[i*4+3] + (float)p3[i*4+3])) * inv;
            ((float4*)op)[i] = v;
        }
    }
}

// ---------------------------------------------------------------------------
extern "C" void kernel_launch(void* const* d_in, const int* in_sizes, int n_in,
                              void* d_out, int out_size, void* d_ws, size_t ws_size,
                              hipStream_t stream) {
    const float* x  = (const float*)d_in[0];
    const float* Wq = (const float*)d_in[1];
    const float* Wk = (const float*)d_in[2];
    const float* Wv = (const float*)d_in[3];

    // workspace (u16): Wb [384][1024]; QF, KF, VF fragment-tiled (2M u16 each)
    unsigned short* Wb = (unsigned short*)d_ws;
    unsigned short* QFw = Wb + (size_t)3 * HH * CC;
    unsigned short* KFw = QFw + (size_t)BB * TT * HH;
    unsigned short* VFw = KFw + (size_t)BB * TT * HH;

    wconv<<<dim3(192), 256, 0, stream>>>(Wq, Wk, Wv, Wb);
    qkv_proj<<<dim3(256), 512, 0, stream>>>(x, Wb, QFw, KFw, VFw);
    attn<<<dim3(512), 512, 0, stream>>>(QFw, KFw, VFw, (float*)d_out);
}

// Round 11
// 145.549 us; speedup vs baseline: 1.0972x; 1.0718x over previous
//
#include <hip/hip_runtime.h>
#include <hip/hip_bf16.h>
#include <stdint.h>

// Problem constants: B=8, T=2048, C=1024 (n_embd), H=128 (head dim)
#define BB 8
#define TT 2048
#define CC 1024
#define HH 128
#define VTP 2112      // Vt row pitch (u16): 4224 B, breaks 4 KB set-aliasing

typedef __attribute__((ext_vector_type(8))) short bf16x8;
typedef __attribute__((ext_vector_type(8))) unsigned short u16x8;
typedef __attribute__((ext_vector_type(4))) float f32x4;
typedef __attribute__((ext_vector_type(16))) float f32x16;

static __device__ __forceinline__ unsigned short f2bf(float f) {
    union { float f; uint32_t u; } v; v.f = f;
    return (unsigned short)((v.u + 0x7fffu + ((v.u >> 16) & 1u)) >> 16);  // RNE
}

#define GLOBAL_AS __attribute__((address_space(1)))
#define LDS_AS    __attribute__((address_space(3)))
static __device__ __forceinline__ void async16(const void* g, void* l) {
    // global->LDS DMA, 16 B/lane; LDS dest = wave-uniform base + lane*16
    __builtin_amdgcn_global_load_lds((const GLOBAL_AS void*)g, (LDS_AS void*)l, 16, 0, 0);
}

// ---------------------------------------------------------------------------
// Kernel 0: W fp32 [k][n] -> bf16 Wb [3*128 n][1024 k]  (k-contiguous rows)
// ---------------------------------------------------------------------------
__global__ __launch_bounds__(256) void wconv(
    const float* __restrict__ Wq, const float* __restrict__ Wk,
    const float* __restrict__ Wv, unsigned short* __restrict__ Wb)
{
    int u = blockIdx.x * 256 + threadIdx.x;
    if (u >= 3 * 128 * 128) return;
    int kc = u & 127, n = (u >> 7) & 127, mat = u >> 14;
    const float* W = (mat == 0) ? Wq : (mat == 1) ? Wk : Wv;
    const float* s = W + (size_t)(kc * 8) * HH + n;
    u16x8 v;
    #pragma unroll
    for (int j = 0; j < 8; j++) v[j] = f2bf(s[(size_t)j * HH]);
    *(u16x8*)(Wb + ((size_t)mat * HH + n) * CC + kc * 8) = v;
}

// ---------------------------------------------------------------------------
// Kernel 1: fused QKV projection. BM=64, 512 threads (8 waves = 2 m-halves x
// 4 n-quarters, each 32m x 96n, 24 MFMA/step), grid 256. BK=64, XOR-swizzled
// Bs via async16; x reg-prefetch after barrier. Emits row-major Q,K and
// transposed Vt (R12/R13 layout -- fragment tiling reverted with R16).
// ---------------------------------------------------------------------------
#define BS_U16 4608              // As = 64 rows * 72 pitch
#define EQ_OFF 0
#define EK_OFF 8704
#define EV_OFF 17408
__global__ __launch_bounds__(512) void qkv_proj(
    const float* __restrict__ x, const unsigned short* __restrict__ Wb,
    unsigned short* __restrict__ Q, unsigned short* __restrict__ K,
    unsigned short* __restrict__ Vt)
{
    __shared__ __align__(16) unsigned short lds[29184];   // 58.37 KB

    const int m0  = blockIdx.x * 64;
    const int tid = threadIdx.x;
    const int lane = tid & 63;
    const int w    = tid >> 6;       // 0..7
    const int qd   = lane >> 4;
    const int ln   = lane & 15;
    const int wm   = w & 1;          // m half (32 rows)
    const int wn   = w >> 1;         // n quarter (96 cols)

    f32x4 acc[2][6];
    #pragma unroll
    for (int i = 0; i < 2; i++)
        #pragma unroll
        for (int j = 0; j < 6; j++) acc[i][j] = (f32x4){0.f,0.f,0.f,0.f};

    const int xr = tid >> 3;         // 0..63 row
    const int xg = (tid & 7) * 8;    // col offset (8 floats / thread)

    float4 xf[2];
    {
        const float* s = x + (size_t)(m0 + xr) * CC + xg;
        xf[0] = ((const float4*)s)[0];
        xf[1] = ((const float4*)s)[1];
    }

    for (int k0 = 0; k0 < CC; k0 += 64) {
        {
            u16x8 v0;
            v0[0]=f2bf(xf[0].x); v0[1]=f2bf(xf[0].y); v0[2]=f2bf(xf[0].z); v0[3]=f2bf(xf[0].w);
            v0[4]=f2bf(xf[1].x); v0[5]=f2bf(xf[1].y); v0[6]=f2bf(xf[1].z); v0[7]=f2bf(xf[1].w);
            *(u16x8*)&lds[xr * 72 + xg] = v0;
        }
        // Bs: 384 rows x 64 k (bf16), 16B chunks, XOR swizzle (^row&7).
        #pragma unroll
        for (int i = 0; i < 6; i++) {
            int sb = i * 512 + w * 64;
            int slot = sb + lane;
            int row = slot >> 3, j = (slot & 7) ^ (row & 7);
            async16(Wb + (size_t)row * CC + k0 + j * 8, &lds[BS_U16 + sb * 8]);
        }
        __syncthreads();
        if (k0 + 64 < CC) {
            const float* s = x + (size_t)(m0 + xr) * CC + k0 + 64 + xg;
            xf[0] = ((const float4*)s)[0];
            xf[1] = ((const float4*)s)[1];
        }
        #pragma unroll
        for (int ks = 0; ks < 2; ks++) {
            bf16x8 a0 = *(const bf16x8*)&lds[(wm*32 + ln) * 72 + ks*32 + qd*8];
            bf16x8 a1 = *(const bf16x8*)&lds[(wm*32 + 16 + ln) * 72 + ks*32 + qd*8];
            #pragma unroll
            for (int nf = 0; nf < 6; nf++) {
                int row = wn * 96 + nf * 16 + ln;
                int ch  = (ks * 4 + qd) ^ (row & 7);
                bf16x8 b = *(const bf16x8*)&lds[BS_U16 + (row * 8 + ch) * 8];
                acc[0][nf] = __builtin_amdgcn_mfma_f32_16x16x32_bf16(a0, b, acc[0][nf], 0, 0, 0);
                acc[1][nf] = __builtin_amdgcn_mfma_f32_16x16x32_bf16(a1, b, acc[1][nf], 0, 0, 0);
            }
        }
        __syncthreads();
    }

    // epilogue: scatter acc -> LDS (Q/K row-major pitch 136; V transposed pitch 72)
    #pragma unroll
    for (int mf = 0; mf < 2; mf++)
        #pragma unroll
        for (int nf = 0; nf < 6; nf++) {
            int n = wn * 96 + nf * 16;
            int mat = n >> 7, hb = n & 127;
            #pragma unroll
            for (int r = 0; r < 4; r++) {
                unsigned short v = f2bf(acc[mf][nf][r]);
                int mrow = wm*32 + mf*16 + qd*4 + r;       // 0..63
                if (mat < 2) lds[(mat ? EK_OFF : EQ_OFF) + mrow * 136 + hb + ln] = v;
                else         lds[EV_OFF + (hb + ln) * 72 + mrow] = v;
            }
        }
    __syncthreads();
    {
        int rr = tid >> 3, c0 = (tid & 7) * 16;            // 64 rows x 8 thr
        #pragma unroll
        for (int i = 0; i < 2; i++) {
            u16x8 vq = *(const u16x8*)&lds[EQ_OFF + rr * 136 + c0 + i * 8];
            *(u16x8*)(Q + (size_t)(m0 + rr) * HH + c0 + i * 8) = vq;
            u16x8 vk = *(const u16x8*)&lds[EK_OFF + rr * 136 + c0 + i * 8];
            *(u16x8*)(K + (size_t)(m0 + rr) * HH + c0 + i * 8) = vk;
        }
    }
    {
        int bb = m0 >> 11, t0 = m0 & (TT - 1);
        int hh = tid >> 2, tf = (tid & 3) * 16;            // 128 h x 4 thr
        #pragma unroll
        for (int i = 0; i < 2; i++) {
            u16x8 vv = *(const u16x8*)&lds[EV_OFF + hh * 72 + tf + i * 8];
            *(u16x8*)(Vt + ((size_t)bb * HH + hh) * VTP + t0 + tf + i * 8) = vv;
        }
    }
}

// ---------------------------------------------------------------------------
// Kernel 2: flash attention (causal), no-max softmax.
// R17: m214-style 32x32 swapped-QK^T + in-register softmax on the R13 staged
// skeleton (rate was invariant across occupancy/barriers/balance/load-source
// -> cut instructions + serial phases per unit work). Per 32q x 32k wave
// tile: S^T = mfma_32x32x16(A=K, B=Q) x8 h-slices -> lane holds 16 P values
// for ONE q-row (q = lane&31, keys crow(r,hi) = (r&3)+8*(r>>2)+4*(lane>>5)).
// Softmax lane-local; P->bf16 via 8 v_cvt_pk_bf16_f32 + 4 v_permlane32_swap
// (builds PV A-fragments in registers -- NO P LDS round-trip, NO f2bf
// scatter). PV: 8 mfma_32x32x16 (2 kslices x 4 h-tiles). MFMA count halved.
// Skeleton from R13: QBLK=64, 512 thr, 8 waves = 2 qgrp(32q) x 4 kq(32k);
// KVBLK=128 double-buffered async16 staging, 1 barrier/step with prefetch.
// LDS 129 KB dynamic (Om merge overlays Ks dbuf). Grid 256 = 8b x 32qt.
// ---------------------------------------------------------------------------
__global__ __launch_bounds__(512) void attn(
    const unsigned short* __restrict__ Q, const unsigned short* __restrict__ K,
    const unsigned short* __restrict__ Vt, float* __restrict__ out)
{
    extern __shared__ __align__(16) unsigned short dyn[];
    unsigned short* KsB = dyn;               // [2][128*128] 64 KB (merge overlay)
    unsigned short* VsB = dyn + 32768;       // [2][128*128] 64 KB
    float*          Lp  = (float*)(dyn + 65536);  // [8][32] 1 KB (132 KB total)

    const int tid  = threadIdx.x;
    const int lane = tid & 63;
    const int wave = tid >> 6;            // 0..7
    const int q32  = lane & 31;           // this lane's q-row within wave tile
    const int hi   = lane >> 5;           // key/k half selector
    const int qgrp = wave >> 2;           // 0..1: q rows qgrp*32..+32
    const int kq   = wave & 3;            // key quarter (32 keys of 128)

    const int bx = blockIdx.x;
    const int b  = bx & 7;                // batch fastest -> XCD spread
    const int qt = bx >> 3;               // 0..31, QBLK=64
    const int qbase = qt * 64 + qgrp * 32;
    const int nst = (qt + 2) >> 1;        // 128-key steps

    const unsigned short* Qb = Q  + (size_t)b * TT * HH;
    const unsigned short* Kb = K  + (size_t)b * TT * HH;
    const unsigned short* Vb = Vt + (size_t)b * HH * VTP;

    // Q B-fragments (swapped QK): lane holds Q[qbase+q32][hs*16 + hi*8 ..+7]
    bf16x8 bq[8];
    #pragma unroll
    for (int hs = 0; hs < 8; hs++)
        bq[hs] = *(const bf16x8*)(Qb + (size_t)(qbase + q32) * HH + hs * 16 + hi * 8);

    f32x16 O[4];
    #pragma unroll
    for (int ht = 0; ht < 4; ht++)
        #pragma unroll
        for (int r = 0; r < 16; r++) O[ht][r] = 0.f;
    float lsum = 0.f;                     // partial row-sum for q = qbase+q32

    const float sl   = 0.08838834764831843f * 1.4426950408889634f; // (1/sqrt128)*log2e
    const float M0L2 = 7.2134752044448f;                           // 5.0*log2(e)

    // ---- staging: K 128 rows x 16 chunks, V 128 h x 16 chunks; XOR ^row&15;
    //      2048 chunks each / 512 lanes = 4 async16 rounds each ----
    #define STAGE(S0, BUF)                                                              \
        do {                                                                            \
            _Pragma("unroll")                                                           \
            for (int i = 0; i < 4; i++) {                                               \
                int sb = i * 512 + wave * 64;                                           \
                int slot = sb + lane;                                                   \
                int row = slot >> 4, jj = (slot & 15) ^ (row & 15);                     \
                async16(Kb + (size_t)((S0) + row) * HH + jj * 8,                        \
                        KsB + (size_t)(BUF) * 16384 + sb * 8);                          \
            }                                                                           \
            _Pragma("unroll")                                                           \
            for (int i = 0; i < 4; i++) {                                               \
                int sb = i * 512 + wave * 64;                                           \
                int slot = sb + lane;                                                   \
                int row = slot >> 4, jj = (slot & 15) ^ (row & 15);                     \
                async16(Vb + (size_t)row * VTP + (S0) + jj * 8,                         \
                        VsB + (size_t)(BUF) * 16384 + sb * 8);                          \
            }                                                                           \
        } while (0)

    STAGE(0, 0);
    for (int st = 0; st < nst; st++) {
        __syncthreads();                  // drains prev STAGE (each wave drains own DMAs)
        if (st + 1 < nst) STAGE((st + 1) * 128, (st + 1) & 1);
        const int buf = st & 1;
        const unsigned short* Ks = KsB + (size_t)buf * 16384;
        const unsigned short* Vs = VsB + (size_t)buf * 16384;
        const int s0 = st * 128;

        // ---- S^T = K Q^T : one 32x32 tile (keys kq*32.. x q 32) ----
        f32x16 s;
        #pragma unroll
        for (int r = 0; r < 16; r++) s[r] = 0.f;
        const int krow = kq * 32 + q32;
        #pragma unroll
        for (int hs = 0; hs < 8; hs++) {
            bf16x8 ak = *(const bf16x8*)&Ks[krow * 128 + (((hs*2 + hi) ^ (krow & 15))) * 8];
            s = __builtin_amdgcn_mfma_f32_32x32x16_bf16(ak, bq[hs], s, 0, 0, 0);
        }
        // ---- in-register softmax: exp2 + causal mask + lane-local lsum ----
        float p[16];
        #pragma unroll
        for (int r = 0; r < 16; r++) {
            int key = s0 + kq * 32 + (r & 3) + 8 * (r >> 2) + 4 * hi;
            float e = __builtin_amdgcn_exp2f(s[r] * sl - M0L2);
            e = (key <= qbase + q32) ? e : 0.f;
            lsum += e;
            p[r] = e;
        }
        // ---- P -> bf16 A-fragments: cvt_pk pairs + permlane32 row swaps ----
        unsigned int w0, w1, w2, w3, w4, w5, w6, w7;
        asm("v_cvt_pk_bf16_f32 %0, %1, %2" : "=v"(w0) : "v"(p[0]),  "v"(p[1]));
        asm("v_cvt_pk_bf16_f32 %0, %1, %2" : "=v"(w1) : "v"(p[2]),  "v"(p[3]));
        asm("v_cvt_pk_bf16_f32 %0, %1, %2" : "=v"(w2) : "v"(p[4]),  "v"(p[5]));
        asm("v_cvt_pk_bf16_f32 %0, %1, %2" : "=v"(w3) : "v"(p[6]),  "v"(p[7]));
        asm("v_cvt_pk_bf16_f32 %0, %1, %2" : "=v"(w4) : "v"(p[8]),  "v"(p[9]));
        asm("v_cvt_pk_bf16_f32 %0, %1, %2" : "=v"(w5) : "v"(p[10]), "v"(p[11]));
        asm("v_cvt_pk_bf16_f32 %0, %1, %2" : "=v"(w6) : "v"(p[12]), "v"(p[13]));
        asm("v_cvt_pk_bf16_f32 %0, %1, %2" : "=v"(w7) : "v"(p[14]), "v"(p[15]));
        // swap hi-lane halves: after, lo lanes hold keys 0-7 / hi lanes 8-15 (ks0)
        asm volatile("v_permlane32_swap_b32 %0, %1" : "+v"(w0), "+v"(w2));
        asm volatile("v_permlane32_swap_b32 %0, %1" : "+v"(w1), "+v"(w3));
        asm volatile("v_permlane32_swap_b32 %0, %1" : "+v"(w4), "+v"(w6));
        asm volatile("v_permlane32_swap_b32 %0, %1" : "+v"(w5), "+v"(w7));
        union { unsigned int u[4]; bf16x8 v; } pa0, pa1;
        pa0.u[0] = w0; pa0.u[1] = w1; pa0.u[2] = w2; pa0.u[3] = w3;
        pa1.u[0] = w4; pa1.u[1] = w5; pa1.u[2] = w6; pa1.u[3] = w7;
        // ---- O += P V : 2 kslices x 4 h-tiles of 32x32x16 ----
        #pragma unroll
        for (int ht = 0; ht < 4; ht++) {
            const int vrow = ht * 32 + q32;    // h row in Vs
            bf16x8 bv0 = *(const bf16x8*)&Vs[vrow * 128 + (((kq*4 + 0 + hi) ^ (vrow & 15))) * 8];
            O[ht] = __builtin_amdgcn_mfma_f32_32x32x16_bf16(pa0.v, bv0, O[ht], 0, 0, 0);
            bf16x8 bv1 = *(const bf16x8*)&Vs[vrow * 128 + (((kq*4 + 2 + hi) ^ (vrow & 15))) * 8];
            O[ht] = __builtin_amdgcn_mfma_f32_32x32x16_bf16(pa1.v, bv1, O[ht], 0, 0, 0);
        }
    }

    // ---- end: combine lane pairs (same q), stash l and O; merge quarters ----
    __syncthreads();                      // all waves done with Ks/Vs
    lsum += __shfl_xor(lsum, 32, 64);
    if (hi == 0) Lp[wave * 32 + q32] = lsum;
    _Float16* om = (_Float16*)KsB + (size_t)wave * 32 * 128;
    #pragma unroll
    for (int ht = 0; ht < 4; ht++)
        #pragma unroll
        for (int r = 0; r < 16; r++)
            om[((r & 3) + 8 * (r >> 2) + 4 * hi) * 128 + ht * 32 + q32] = (_Float16)O[ht][r];
    __syncthreads();

    // ---- 4-way merge (key quarters) + write: 64 rows x 8 thr, 16 h each ----
    {
        int row = tid >> 3, h0 = (tid & 7) * 16;
        int g = row >> 5, rl = row & 31;       // g = qgrp of this row
        float L = Lp[(g*4 + 0)*32 + rl] + Lp[(g*4 + 1)*32 + rl]
                + Lp[(g*4 + 2)*32 + rl] + Lp[(g*4 + 3)*32 + rl];
        float inv = 1.0f / L;
        const _Float16* p0 = (const _Float16*)KsB + (size_t)(g*4 + 0) * 4096 + rl * 128 + h0;
        const _Float16* p1 = p0 + 4096;
        const _Float16* p2 = p1 + 4096;
        const _Float16* p3 = p2 + 4096;
        float* op = out + ((size_t)b * TT + qt * 64 + row) * HH + h0;
        #pragma unroll
        for (int i = 0; i < 4; i++) {
            float4 v;
            v.x = (((float)p0[i*4+0] + (float)p1[i*4+0]) + ((float)p2[i*4+0] + (float)p3[i*4+0])) * inv;
            v.y = (((float)p0[i*4+1] + (float)p1[i*4+1]) + ((float)p2[i*4+1] + (float)p3[i*4+1])) * inv;
            v.z = (((float)p0[i*4+2] + (float)p1[i*4+2]) + ((float)p2[i*4+2] + (float)p3[i*4+2])) * inv;
            v.w = (((float)p0[i*4+3] + (float)p1[i*4+3]) + ((float)p2[i*4+3] + (float)p3[i*4+3])) * inv;
            ((float4*)op)[i] = v;
        }
    }
    #undef STAGE
}

// ---------------------------------------------------------------------------
extern "C" void kernel_launch(void* const* d_in, const int* in_sizes, int n_in,
                              void* d_out, int out_size, void* d_ws, size_t ws_size,
                              hipStream_t stream) {
    const float* x  = (const float*)d_in[0];
    const float* Wq = (const float*)d_in[1];
    const float* Wk = (const float*)d_in[2];
    const float* Wv = (const float*)d_in[3];

    // workspace (u16): Wb [384][1024]; Q,K [16384][128]; Vt [8][128][VTP]
    unsigned short* Wb = (unsigned short*)d_ws;
    unsigned short* Qw = Wb + (size_t)3 * HH * CC;
    unsigned short* Kw = Qw + (size_t)BB * TT * HH;
    unsigned short* Vw = Kw + (size_t)BB * TT * HH;

    // 132 KB dynamic LDS for attn (>64 KB default cap)
    static bool attr_done = false;
    if (!attr_done) {
        hipFuncSetAttribute((const void*)attn,
                            hipFuncAttributeMaxDynamicSharedMemorySize, 132096);
        attr_done = true;
    }

    wconv<<<dim3(192), 256, 0, stream>>>(Wq, Wk, Wv, Wb);
    qkv_proj<<<dim3(256), 512, 0, stream>>>(x, Wb, Qw, Kw, Vw);
    attn<<<dim3(256), 512, 132096, stream>>>(Qw, Kw, Vw, (float*)d_out);
}